// Round 20
// baseline (1698.047 us; speedup 1.0000x reference)
//
#include <hip/hip_runtime.h>
#include <hip/hip_bf16.h>
#include <stdint.h>

#define T_DIM 4096
#define K_DIM 4096
#define N_DIM 11008

// ws layout (bytes): xq int8[T*K] | xs f32[T] | w8 int8[N*K]
#define XQ_OFF 0
#define XS_OFF 16777216
#define W8_OFF 16793600

typedef __attribute__((ext_vector_type(4))) int v4i;

// ---------------------------------------------------------------------------
// Kernel 1: per-token absmax quant (f32 x). Unchanged (r17-verified).
// ---------------------------------------------------------------------------
__global__ __launch_bounds__(256) void quant_kernel(
    const float* __restrict__ x, int8_t* __restrict__ xq, float* __restrict__ xs)
{
    const int wid   = threadIdx.x >> 6;
    const int lane  = threadIdx.x & 63;
    const int token = blockIdx.x * 4 + wid;

    const float* xrow = x + (size_t)token * K_DIM;

    float4 v[16];
    float am = 0.0f;
#pragma unroll
    for (int j = 0; j < 16; ++j) {
        v[j] = *(const float4*)(xrow + (size_t)(j * 64 + lane) * 4);
        am = fmaxf(am, fmaxf(fmaxf(fabsf(v[j].x), fabsf(v[j].y)),
                             fmaxf(fabsf(v[j].z), fabsf(v[j].w))));
    }
#pragma unroll
    for (int m = 1; m < 64; m <<= 1)
        am = fmaxf(am, __shfl_xor(am, m, 64));

    const float scale = fmaxf(am, 1e-5f) / 127.0f;
    if (lane == 0) xs[token] = scale;

    uint32_t* qrow = (uint32_t*)(xq + (size_t)token * K_DIM);
#pragma unroll
    for (int j = 0; j < 16; ++j) {
        int q0 = min(127, max(-127, (int)rintf(v[j].x / scale)));
        int q1 = min(127, max(-127, (int)rintf(v[j].y / scale)));
        int q2 = min(127, max(-127, (int)rintf(v[j].z / scale)));
        int q3 = min(127, max(-127, (int)rintf(v[j].w / scale)));
        qrow[j * 64 + lane] = ((uint32_t)(uint8_t)(int8_t)q0)       |
                              ((uint32_t)(uint8_t)(int8_t)q1 << 8)  |
                              ((uint32_t)(uint8_t)(int8_t)q2 << 16) |
                              ((uint32_t)(uint8_t)(int8_t)q3 << 24);
    }
}

// ---------------------------------------------------------------------------
// Kernel 2: pack int32-widened weights -> int8. Unchanged (r17-verified).
// ---------------------------------------------------------------------------
__global__ __launch_bounds__(256) void pack_w_kernel(
    const int* __restrict__ w32, int8_t* __restrict__ w8)
{
    const size_t tid = (size_t)blockIdx.x * 256 + threadIdx.x;
    const int4* src = (const int4*)w32 + tid * 4;
    uint32_t o[4];
#pragma unroll
    for (int i = 0; i < 4; ++i) {
        int4 a = src[i];
        o[i] = ((uint32_t)a.x & 0xFFu) | (((uint32_t)a.y & 0xFFu) << 8) |
               (((uint32_t)a.z & 0xFFu) << 16) | ((uint32_t)a.w << 24);
    }
    *(uint4*)(w8 + tid * 16) = make_uint4(o[0], o[1], o[2], o[3]);
}

// ---------------------------------------------------------------------------
// Kernel 3: int8 MFMA GEMM — 256x256 tile (87 ops/LDS-byte), 8 waves 2M x 4N,
// 2-buffer distance-1 prefetch (64KB LDS -> 2 blocks/CU). Swizzle, offsets,
// setprio, epilogue mapping verbatim from r18 (refcheck'd twice).
// ---------------------------------------------------------------------------
#define BM 256
#define BN 256
#define BKB 64
#define NT (K_DIM / BKB)     // 64
#define BUF_SZ 16384         // 256 rows x 64 B

__global__ __launch_bounds__(512, 4) void gemm_i8_kernel(
    const int8_t* __restrict__ xq, const int8_t* __restrict__ w8,
    const float* __restrict__ xs, const float* __restrict__ wsc,
    const __hip_bfloat16* __restrict__ bias, float* __restrict__ out)
{
    __shared__ int8_t lds[2 * 2 * BUF_SZ];   // 64 KiB: [buf][A/B][256*64]

    constexpr int NBN = N_DIM / BN;              // 43
    constexpr int NWG = (T_DIM / BM) * NBN;      // 688 (div by 8)
    constexpr int CPX = NWG / 8;                 // 86

    const int bid = blockIdx.x;
    const int b2  = (bid % 8) * CPX + bid / 8;   // bijective XCD swizzle
    const int bm  = b2 / NBN;
    const int bn  = b2 % NBN;

    const int tid  = threadIdx.x;
    const int wid  = tid >> 6;
    const int lane = tid & 63;
    const int wm   = wid >> 2;    // 0..1 (M)
    const int wn   = wid & 3;     // 0..3 (N)

    // fragment LDS byte offsets (chunk-XOR swizzled read side) — r18 verbatim
    const int fr = lane & 15, kg = lane >> 4;
    int offA[8], offB[4];
#pragma unroll
    for (int mi = 0; mi < 8; ++mi) {
        const int row = wm * 128 + mi * 16 + fr;
        offA[mi] = row * 64 + ((kg ^ ((row >> 1) & 3)) << 4);
    }
#pragma unroll
    for (int ni = 0; ni < 4; ++ni) {
        const int row = wn * 64 + ni * 16 + fr;
        offB[ni] = row * 64 + ((kg ^ ((row >> 1) & 3)) << 4);
    }

    // staging: thread -> (row, slot); source chunk pre-swizzled — r18 verbatim
    const int srow  = tid >> 2;
    const int sslot = tid & 3;
    const int r0 = srow, r1 = 128 + srow;
    const int c0 = sslot ^ ((r0 >> 1) & 3);
    const int c1 = sslot ^ ((r1 >> 1) & 3);
    const int8_t* gA0 = xq + (size_t)(bm * BM + r0) * K_DIM + c0 * 16;
    const int8_t* gA1 = xq + (size_t)(bm * BM + r1) * K_DIM + c1 * 16;
    const int8_t* gB0 = w8 + (size_t)(bn * BM + r0) * K_DIM + c0 * 16;
    const int8_t* gB1 = w8 + (size_t)(bn * BM + r1) * K_DIM + c1 * 16;
    const int ldsW = wid * 1024;

    v4i acc[8][4];
#pragma unroll
    for (int mi = 0; mi < 8; ++mi)
#pragma unroll
        for (int ni = 0; ni < 4; ++ni) acc[mi][ni] = (v4i){0, 0, 0, 0};

#define STAGE(bufb, mat, Rr, kt)                                                \
    __builtin_amdgcn_global_load_lds(                                           \
        (const __attribute__((address_space(1))) void*)(                        \
            ((mat) ? ((Rr) ? gB1 : gB0) : ((Rr) ? gA1 : gA0)) +                 \
            (size_t)(kt) * BKB),                                                \
        (__attribute__((address_space(3))) void*)(                              \
            lds + ((bufb) * 2 + (mat)) * BUF_SZ + (Rr) * 8192 + ldsW),          \
        16, 0, 0)

    // prologue: tile 0 -> buf 0
    STAGE(0, 0, 0, 0); STAGE(0, 0, 1, 0); STAGE(0, 1, 0, 0); STAGE(0, 1, 1, 0);
    asm volatile("s_waitcnt vmcnt(0)" ::: "memory");
    __builtin_amdgcn_s_barrier();
    asm volatile("" ::: "memory");

    for (int t = 0; t < NT; ++t) {
        const int p  = t & 1;
        const int pn = p ^ 1;          // buffer consumed at t-1: safe to refill
        const int8_t* bA = lds + (p * 2 + 0) * BUF_SZ;
        const int8_t* bB = lds + (p * 2 + 1) * BUF_SZ;

        // ---- phase 1: read B frags + A frags 0-3; issue A-stage of t+1 ----
        v4i bF[4], aF[4];
#pragma unroll
        for (int ni = 0; ni < 4; ++ni) bF[ni] = *(const v4i*)(bB + offB[ni]);
#pragma unroll
        for (int mi = 0; mi < 4; ++mi) aF[mi] = *(const v4i*)(bA + offA[mi]);
        if (t + 1 < NT) { STAGE(pn, 0, 0, t + 1); STAGE(pn, 0, 1, t + 1); }
        __builtin_amdgcn_s_barrier();
        asm volatile("" ::: "memory");
        __builtin_amdgcn_s_setprio(1);
#pragma unroll
        for (int mi = 0; mi < 4; ++mi)
#pragma unroll
            for (int ni = 0; ni < 4; ++ni)
                acc[mi][ni] = __builtin_amdgcn_mfma_i32_16x16x64_i8(
                    aF[mi], bF[ni], acc[mi][ni], 0, 0, 0);
        __builtin_amdgcn_s_setprio(0);
        __builtin_amdgcn_s_barrier();
        asm volatile("" ::: "memory");

        // ---- phase 2: read A frags 4-7; issue B-stage of t+1 ----
#pragma unroll
        for (int mi = 0; mi < 4; ++mi) aF[mi] = *(const v4i*)(bA + offA[mi + 4]);
        if (t + 1 < NT) { STAGE(pn, 1, 0, t + 1); STAGE(pn, 1, 1, t + 1); }
        __builtin_amdgcn_s_barrier();
        asm volatile("" ::: "memory");
        __builtin_amdgcn_s_setprio(1);
#pragma unroll
        for (int mi = 0; mi < 4; ++mi)
#pragma unroll
            for (int ni = 0; ni < 4; ++ni)
                acc[mi + 4][ni] = __builtin_amdgcn_mfma_i32_16x16x64_i8(
                    aF[mi], bF[ni], acc[mi + 4][ni], 0, 0, 0);
        __builtin_amdgcn_s_setprio(0);
        asm volatile("s_waitcnt vmcnt(0)" ::: "memory");   // t+1 staged (issued ~650cyc ago)
        __builtin_amdgcn_s_barrier();
        asm volatile("" ::: "memory");
    }

    // epilogue (r17/r18-verified mapping; bf16-exact values in f32 slots)
    const int row0 = bm * BM + wm * 128 + (lane >> 4) * 4;
    const int col0 = bn * BN + wn * 64 + (lane & 15);
#pragma unroll
    for (int mi = 0; mi < 8; ++mi) {
#pragma unroll
        for (int j = 0; j < 4; ++j) {
            const int row = row0 + mi * 16 + j;
            const float xscale = xs[row];
#pragma unroll
            for (int ni = 0; ni < 4; ++ni) {
                const int col = col0 + ni * 16;
                float p_  = (float)acc[mi][ni][j] * xscale * wsc[col];
                float pb_ = __bfloat162float(__float2bfloat16(p_));
                float vb  = __bfloat162float(__float2bfloat16(
                                pb_ + __bfloat162float(bias[col])));
                out[(size_t)row * N_DIM + col] = vb;
            }
        }
    }
#undef STAGE
}

// ---------------------------------------------------------------------------
extern "C" void kernel_launch(void* const* d_in, const int* in_sizes, int n_in,
                              void* d_out, int out_size, void* d_ws, size_t ws_size,
                              hipStream_t stream)
{
    const float*          x    = (const float*)d_in[0];
    const int*            w32  = (const int*)d_in[1];
    const float*          wsc  = (const float*)d_in[2];
    const __hip_bfloat16* bias = (const __hip_bfloat16*)d_in[3];
    float*                out  = (float*)d_out;

    int8_t* xq = (int8_t*)d_ws + XQ_OFF;
    float*  xs = (float*)((char*)d_ws + XS_OFF);
    int8_t* w8 = (int8_t*)d_ws + W8_OFF;

    quant_kernel<<<T_DIM / 4, 256, 0, stream>>>(x, xq, xs);
    pack_w_kernel<<<(N_DIM * (K_DIM / 16)) / 256, 256, 0, stream>>>(w32, w8);
    gemm_i8_kernel<<<(T_DIM / BM) * (N_DIM / BN), 512, 0, stream>>>(
        xq, w8, xs, wsc, bias, out);
}

// Round 21
// 269.413 us; speedup vs baseline: 6.3028x; 6.3028x over previous
//
#include <hip/hip_runtime.h>
#include <hip/hip_bf16.h>
#include <stdint.h>

#define T_DIM 4096
#define K_DIM 4096
#define N_DIM 11008

// ws layout (bytes): xq int8[T*K] | xs f32[T] | w8 int8[N*K]
#define XQ_OFF 0
#define XS_OFF 16777216
#define W8_OFF 16793600

typedef __attribute__((ext_vector_type(4))) int v4i;

// ---------------------------------------------------------------------------
// Kernel 1: FUSED quant + pack (concurrent via grid split).
//   blocks [0, 1024): per-token absmax quant of f32 x (r17-verified body)
//   blocks [1024, 12032): int32->int8 weight pack (r17-verified body)
// ---------------------------------------------------------------------------
__global__ __launch_bounds__(256) void prep_kernel(
    const float* __restrict__ x, int8_t* __restrict__ xq, float* __restrict__ xs,
    const int* __restrict__ w32, int8_t* __restrict__ w8)
{
    if (blockIdx.x < T_DIM / 4) {
        const int wid   = threadIdx.x >> 6;
        const int lane  = threadIdx.x & 63;
        const int token = blockIdx.x * 4 + wid;

        const float* xrow = x + (size_t)token * K_DIM;

        float4 v[16];
        float am = 0.0f;
#pragma unroll
        for (int j = 0; j < 16; ++j) {
            v[j] = *(const float4*)(xrow + (size_t)(j * 64 + lane) * 4);
            am = fmaxf(am, fmaxf(fmaxf(fabsf(v[j].x), fabsf(v[j].y)),
                                 fmaxf(fabsf(v[j].z), fabsf(v[j].w))));
        }
#pragma unroll
        for (int m = 1; m < 64; m <<= 1)
            am = fmaxf(am, __shfl_xor(am, m, 64));

        const float scale = fmaxf(am, 1e-5f) / 127.0f;
        if (lane == 0) xs[token] = scale;

        uint32_t* qrow = (uint32_t*)(xq + (size_t)token * K_DIM);
#pragma unroll
        for (int j = 0; j < 16; ++j) {
            int q0 = min(127, max(-127, (int)rintf(v[j].x / scale)));
            int q1 = min(127, max(-127, (int)rintf(v[j].y / scale)));
            int q2 = min(127, max(-127, (int)rintf(v[j].z / scale)));
            int q3 = min(127, max(-127, (int)rintf(v[j].w / scale)));
            qrow[j * 64 + lane] = ((uint32_t)(uint8_t)(int8_t)q0)       |
                                  ((uint32_t)(uint8_t)(int8_t)q1 << 8)  |
                                  ((uint32_t)(uint8_t)(int8_t)q2 << 16) |
                                  ((uint32_t)(uint8_t)(int8_t)q3 << 24);
        }
    } else {
        const size_t tid = (size_t)(blockIdx.x - T_DIM / 4) * 256 + threadIdx.x;
        const int4* src = (const int4*)w32 + tid * 4;
        uint32_t o[4];
#pragma unroll
        for (int i = 0; i < 4; ++i) {
            int4 a = src[i];
            o[i] = ((uint32_t)a.x & 0xFFu) | (((uint32_t)a.y & 0xFFu) << 8) |
                   (((uint32_t)a.z & 0xFFu) << 16) | ((uint32_t)a.w << 24);
        }
        *(uint4*)(w8 + tid * 16) = make_uint4(o[0], o[1], o[2], o[3]);
    }
}

// ---------------------------------------------------------------------------
// Kernel 2: int8 MFMA GEMM — r18 skeleton (256x256, 8 waves, 3-buf rotation,
// counted vmcnt(4), chunk-XOR swizzle, 1 block/CU @ 96KB LDS), refined to a
// 4-phase/K-tile interleave: each phase = {2-4 ds_reads | 1 stage issue |
// barrier | 8-MFMA cluster (setprio) | barrier}.  Epilogue = r17/r18 verbatim.
// ---------------------------------------------------------------------------
#define BM 256
#define BN 256
#define BKB 64
#define NT (K_DIM / BKB)     // 64
#define BUF_SZ 16384         // 256 rows x 64 B

__global__ __launch_bounds__(512, 2) void gemm_i8_kernel(
    const int8_t* __restrict__ xq, const int8_t* __restrict__ w8,
    const float* __restrict__ xs, const float* __restrict__ wsc,
    const __hip_bfloat16* __restrict__ bias, float* __restrict__ out)
{
    __shared__ int8_t lds[3 * 2 * BUF_SZ];   // 96 KiB

    constexpr int NBN = N_DIM / BN;              // 43
    constexpr int NWG = (T_DIM / BM) * NBN;      // 688 (div by 8)
    constexpr int CPX = NWG / 8;                 // 86

    const int bid = blockIdx.x;
    const int b2  = (bid % 8) * CPX + bid / 8;   // bijective XCD swizzle
    const int bm  = b2 / NBN;
    const int bn  = b2 % NBN;

    const int tid  = threadIdx.x;
    const int wid  = tid >> 6;
    const int lane = tid & 63;
    const int wm   = wid >> 2;    // 0..1 (M)
    const int wn   = wid & 3;     // 0..3 (N)

    // fragment LDS byte offsets (chunk-XOR swizzled read side) — r18 verbatim
    const int fr = lane & 15, kg = lane >> 4;
    int offA[8], offB[4];
#pragma unroll
    for (int mi = 0; mi < 8; ++mi) {
        const int row = wm * 128 + mi * 16 + fr;
        offA[mi] = row * 64 + ((kg ^ ((row >> 1) & 3)) << 4);
    }
#pragma unroll
    for (int ni = 0; ni < 4; ++ni) {
        const int row = wn * 64 + ni * 16 + fr;
        offB[ni] = row * 64 + ((kg ^ ((row >> 1) & 3)) << 4);
    }

    // staging addressing (pre-swizzled source) — r18 verbatim
    const int srow  = tid >> 2;
    const int sslot = tid & 3;
    const int r0 = srow, r1 = 128 + srow;
    const int c0 = sslot ^ ((r0 >> 1) & 3);
    const int c1 = sslot ^ ((r1 >> 1) & 3);
    const int8_t* gA0 = xq + (size_t)(bm * BM + r0) * K_DIM + c0 * 16;
    const int8_t* gA1 = xq + (size_t)(bm * BM + r1) * K_DIM + c1 * 16;
    const int8_t* gB0 = w8 + (size_t)(bn * BM + r0) * K_DIM + c0 * 16;
    const int8_t* gB1 = w8 + (size_t)(bn * BM + r1) * K_DIM + c1 * 16;
    const int ldsW = wid * 1024;

    v4i acc[8][4];
#pragma unroll
    for (int mi = 0; mi < 8; ++mi)
#pragma unroll
        for (int ni = 0; ni < 4; ++ni) acc[mi][ni] = (v4i){0, 0, 0, 0};

#define STAGE(bufb, mat, Rr, kt)                                                \
    __builtin_amdgcn_global_load_lds(                                           \
        (const __attribute__((address_space(1))) void*)(                        \
            ((mat) ? ((Rr) ? gB1 : gB0) : ((Rr) ? gA1 : gA0)) +                 \
            (size_t)(kt) * BKB),                                                \
        (__attribute__((address_space(3))) void*)(                              \
            lds + ((bufb) * 2 + (mat)) * BUF_SZ + (Rr) * 8192 + ldsW),          \
        16, 0, 0)

#define MFMA_PAIR(base)                                                         \
    _Pragma("unroll")                                                           \
    for (int mi = 0; mi < 2; ++mi)                                              \
        _Pragma("unroll")                                                       \
        for (int ni = 0; ni < 4; ++ni)                                          \
            acc[(base) + mi][ni] = __builtin_amdgcn_mfma_i32_16x16x64_i8(       \
                aF[mi], bF[ni], acc[(base) + mi][ni], 0, 0, 0)

    // prologue: tiles 0 -> buf0, 1 -> buf1
    STAGE(0, 0, 0, 0); STAGE(0, 0, 1, 0); STAGE(0, 1, 0, 0); STAGE(0, 1, 1, 0);
    STAGE(1, 0, 0, 1); STAGE(1, 0, 1, 1); STAGE(1, 1, 0, 1); STAGE(1, 1, 1, 1);
    asm volatile("s_waitcnt vmcnt(4)" ::: "memory");   // tile 0 landed
    __builtin_amdgcn_s_barrier();
    asm volatile("" ::: "memory");

    for (int t = 0; t < NT; ++t) {
        const int b  = t % 3;
        const int pb = (t + 2) % 3;    // consumed at t-1: safe to refill
        const int8_t* bA = lds + (b * 2 + 0) * BUF_SZ;
        const int8_t* bB = lds + (b * 2 + 1) * BUF_SZ;
        const bool pf = (t + 2 < NT);

        v4i bF[4], aF[2];

        // ---- phase 1: B frags + A01; stage A-r0 ----
#pragma unroll
        for (int ni = 0; ni < 4; ++ni) bF[ni] = *(const v4i*)(bB + offB[ni]);
        aF[0] = *(const v4i*)(bA + offA[0]);
        aF[1] = *(const v4i*)(bA + offA[1]);
        if (pf) STAGE(pb, 0, 0, t + 2);
        __builtin_amdgcn_s_barrier();
        asm volatile("" ::: "memory");
        __builtin_amdgcn_s_setprio(1);
        MFMA_PAIR(0);
        __builtin_amdgcn_s_setprio(0);
        __builtin_amdgcn_s_barrier();
        asm volatile("" ::: "memory");

        // ---- phase 2: A23; stage A-r1 ----
        aF[0] = *(const v4i*)(bA + offA[2]);
        aF[1] = *(const v4i*)(bA + offA[3]);
        if (pf) STAGE(pb, 0, 1, t + 2);
        __builtin_amdgcn_s_barrier();
        asm volatile("" ::: "memory");
        __builtin_amdgcn_s_setprio(1);
        MFMA_PAIR(2);
        __builtin_amdgcn_s_setprio(0);
        __builtin_amdgcn_s_barrier();
        asm volatile("" ::: "memory");

        // ---- phase 3: A45; stage B-r0 ----
        aF[0] = *(const v4i*)(bA + offA[4]);
        aF[1] = *(const v4i*)(bA + offA[5]);
        if (pf) STAGE(pb, 1, 0, t + 2);
        __builtin_amdgcn_s_barrier();
        asm volatile("" ::: "memory");
        __builtin_amdgcn_s_setprio(1);
        MFMA_PAIR(4);
        __builtin_amdgcn_s_setprio(0);
        __builtin_amdgcn_s_barrier();
        asm volatile("" ::: "memory");

        // ---- phase 4: A67; stage B-r1; counted drain ----
        aF[0] = *(const v4i*)(bA + offA[6]);
        aF[1] = *(const v4i*)(bA + offA[7]);
        if (pf) STAGE(pb, 1, 1, t + 2);
        __builtin_amdgcn_s_barrier();
        asm volatile("" ::: "memory");
        __builtin_amdgcn_s_setprio(1);
        MFMA_PAIR(6);
        __builtin_amdgcn_s_setprio(0);
        if (t < NT - 2) asm volatile("s_waitcnt vmcnt(4)" ::: "memory");
        else            asm volatile("s_waitcnt vmcnt(0)" ::: "memory");
        __builtin_amdgcn_s_barrier();
        asm volatile("" ::: "memory");
    }

    // epilogue (r17/r18-verified mapping; bf16-exact values in f32 slots)
    const int row0 = bm * BM + wm * 128 + (lane >> 4) * 4;
    const int col0 = bn * BN + wn * 64 + (lane & 15);
#pragma unroll
    for (int mi = 0; mi < 8; ++mi) {
#pragma unroll
        for (int j = 0; j < 4; ++j) {
            const int row = row0 + mi * 16 + j;
            const float xscale = xs[row];
#pragma unroll
            for (int ni = 0; ni < 4; ++ni) {
                const int col = col0 + ni * 16;
                float p_  = (float)acc[mi][ni][j] * xscale * wsc[col];
                float pb_ = __bfloat162float(__float2bfloat16(p_));
                float vb  = __bfloat162float(__float2bfloat16(
                                pb_ + __bfloat162float(bias[col])));
                out[(size_t)row * N_DIM + col] = vb;
            }
        }
    }
#undef STAGE
#undef MFMA_PAIR
}

// ---------------------------------------------------------------------------
extern "C" void kernel_launch(void* const* d_in, const int* in_sizes, int n_in,
                              void* d_out, int out_size, void* d_ws, size_t ws_size,
                              hipStream_t stream)
{
    const float*          x    = (const float*)d_in[0];
    const int*            w32  = (const int*)d_in[1];
    const float*          wsc  = (const float*)d_in[2];
    const __hip_bfloat16* bias = (const __hip_bfloat16*)d_in[3];
    float*                out  = (float*)d_out;

    int8_t* xq = (int8_t*)d_ws + XQ_OFF;
    float*  xs = (float*)((char*)d_ws + XS_OFF);
    int8_t* w8 = (int8_t*)d_ws + W8_OFF;

    prep_kernel<<<T_DIM / 4 + (N_DIM * (K_DIM / 16)) / 256, 256, 0, stream>>>(
        x, xq, xs, w32, w8);
    gemm_i8_kernel<<<(T_DIM / BM) * (N_DIM / BN), 512, 0, stream>>>(
        xq, w8, xs, wsc, bias, out);
}

// Round 22
// 264.659 us; speedup vs baseline: 6.4160x; 1.0180x over previous
//
#include <hip/hip_runtime.h>
#include <hip/hip_bf16.h>
#include <stdint.h>

#define T_DIM 4096
#define K_DIM 4096
#define N_DIM 11008

// ws layout (bytes): xq int8[T*K] | xs f32[T] | w8 int8[N*K]
#define XQ_OFF 0
#define XS_OFF 16777216
#define W8_OFF 16793600

typedef __attribute__((ext_vector_type(4))) int v4i;

// ---------------------------------------------------------------------------
// Kernel 1: FUSED quant + pack (grid-split, r21-verified).
// ---------------------------------------------------------------------------
__global__ __launch_bounds__(256) void prep_kernel(
    const float* __restrict__ x, int8_t* __restrict__ xq, float* __restrict__ xs,
    const int* __restrict__ w32, int8_t* __restrict__ w8)
{
    if (blockIdx.x < T_DIM / 4) {
        const int wid   = threadIdx.x >> 6;
        const int lane  = threadIdx.x & 63;
        const int token = blockIdx.x * 4 + wid;

        const float* xrow = x + (size_t)token * K_DIM;

        float4 v[16];
        float am = 0.0f;
#pragma unroll
        for (int j = 0; j < 16; ++j) {
            v[j] = *(const float4*)(xrow + (size_t)(j * 64 + lane) * 4);
            am = fmaxf(am, fmaxf(fmaxf(fabsf(v[j].x), fabsf(v[j].y)),
                                 fmaxf(fabsf(v[j].z), fabsf(v[j].w))));
        }
#pragma unroll
        for (int m = 1; m < 64; m <<= 1)
            am = fmaxf(am, __shfl_xor(am, m, 64));

        const float scale = fmaxf(am, 1e-5f) / 127.0f;
        if (lane == 0) xs[token] = scale;

        uint32_t* qrow = (uint32_t*)(xq + (size_t)token * K_DIM);
#pragma unroll
        for (int j = 0; j < 16; ++j) {
            int q0 = min(127, max(-127, (int)rintf(v[j].x / scale)));
            int q1 = min(127, max(-127, (int)rintf(v[j].y / scale)));
            int q2 = min(127, max(-127, (int)rintf(v[j].z / scale)));
            int q3 = min(127, max(-127, (int)rintf(v[j].w / scale)));
            qrow[j * 64 + lane] = ((uint32_t)(uint8_t)(int8_t)q0)       |
                                  ((uint32_t)(uint8_t)(int8_t)q1 << 8)  |
                                  ((uint32_t)(uint8_t)(int8_t)q2 << 16) |
                                  ((uint32_t)(uint8_t)(int8_t)q3 << 24);
        }
    } else {
        const size_t tid = (size_t)(blockIdx.x - T_DIM / 4) * 256 + threadIdx.x;
        const int4* src = (const int4*)w32 + tid * 4;
        uint32_t o[4];
#pragma unroll
        for (int i = 0; i < 4; ++i) {
            int4 a = src[i];
            o[i] = ((uint32_t)a.x & 0xFFu) | (((uint32_t)a.y & 0xFFu) << 8) |
                   (((uint32_t)a.z & 0xFFu) << 16) | ((uint32_t)a.w << 24);
        }
        *(uint4*)(w8 + tid * 16) = make_uint4(o[0], o[1], o[2], o[3]);
    }
}

// ---------------------------------------------------------------------------
// Kernel 2: int8 MFMA GEMM — 256x256, 8 waves, 3-buf distance-2 rotation,
// SINGLE barrier + counted vmcnt per K-tile (waves free to drift within the
// tile -> LDS reads of one wave overlap MFMAs of another). Race-free: stage
// target (t+2)%3 was fully consumed before the end-of-(t-1) barrier.
// Swizzle/offsets/prologue/epilogue verbatim from r18/r21 (refcheck'd).
// ---------------------------------------------------------------------------
#define BM 256
#define BN 256
#define BKB 64
#define NT (K_DIM / BKB)     // 64
#define BUF_SZ 16384         // 256 rows x 64 B

__global__ __launch_bounds__(512, 2) void gemm_i8_kernel(
    const int8_t* __restrict__ xq, const int8_t* __restrict__ w8,
    const float* __restrict__ xs, const float* __restrict__ wsc,
    const __hip_bfloat16* __restrict__ bias, float* __restrict__ out)
{
    __shared__ int8_t lds[3 * 2 * BUF_SZ];   // 96 KiB

    constexpr int NBN = N_DIM / BN;              // 43
    constexpr int NWG = (T_DIM / BM) * NBN;      // 688 (div by 8)
    constexpr int CPX = NWG / 8;                 // 86

    const int bid = blockIdx.x;
    const int b2  = (bid % 8) * CPX + bid / 8;   // bijective XCD swizzle
    const int bm  = b2 / NBN;
    const int bn  = b2 % NBN;

    const int tid  = threadIdx.x;
    const int wid  = tid >> 6;
    const int lane = tid & 63;
    const int wm   = wid >> 2;    // 0..1 (M)
    const int wn   = wid & 3;     // 0..3 (N)

    // fragment LDS byte offsets (chunk-XOR swizzled read side)
    const int fr = lane & 15, kg = lane >> 4;
    int offA[8], offB[4];
#pragma unroll
    for (int mi = 0; mi < 8; ++mi) {
        const int row = wm * 128 + mi * 16 + fr;
        offA[mi] = row * 64 + ((kg ^ ((row >> 1) & 3)) << 4);
    }
#pragma unroll
    for (int ni = 0; ni < 4; ++ni) {
        const int row = wn * 64 + ni * 16 + fr;
        offB[ni] = row * 64 + ((kg ^ ((row >> 1) & 3)) << 4);
    }

    // staging addressing (pre-swizzled source)
    const int srow  = tid >> 2;
    const int sslot = tid & 3;
    const int r0 = srow, r1 = 128 + srow;
    const int c0 = sslot ^ ((r0 >> 1) & 3);
    const int c1 = sslot ^ ((r1 >> 1) & 3);
    const int8_t* gA0 = xq + (size_t)(bm * BM + r0) * K_DIM + c0 * 16;
    const int8_t* gA1 = xq + (size_t)(bm * BM + r1) * K_DIM + c1 * 16;
    const int8_t* gB0 = w8 + (size_t)(bn * BM + r0) * K_DIM + c0 * 16;
    const int8_t* gB1 = w8 + (size_t)(bn * BM + r1) * K_DIM + c1 * 16;
    const int ldsW = wid * 1024;

    v4i acc[8][4];
#pragma unroll
    for (int mi = 0; mi < 8; ++mi)
#pragma unroll
        for (int ni = 0; ni < 4; ++ni) acc[mi][ni] = (v4i){0, 0, 0, 0};

#define STAGE(bufb, mat, Rr, kt)                                                \
    __builtin_amdgcn_global_load_lds(                                           \
        (const __attribute__((address_space(1))) void*)(                        \
            ((mat) ? ((Rr) ? gB1 : gB0) : ((Rr) ? gA1 : gA0)) +                 \
            (size_t)(kt) * BKB),                                                \
        (__attribute__((address_space(3))) void*)(                              \
            lds + ((bufb) * 2 + (mat)) * BUF_SZ + (Rr) * 8192 + ldsW),          \
        16, 0, 0)

    // prologue: tiles 0 -> buf0, 1 -> buf1
    STAGE(0, 0, 0, 0); STAGE(0, 0, 1, 0); STAGE(0, 1, 0, 0); STAGE(0, 1, 1, 0);
    STAGE(1, 0, 0, 1); STAGE(1, 0, 1, 1); STAGE(1, 1, 0, 1); STAGE(1, 1, 1, 1);
    asm volatile("s_waitcnt vmcnt(4)" ::: "memory");   // tile 0 landed
    __builtin_amdgcn_s_barrier();
    asm volatile("" ::: "memory");

    for (int t = 0; t < NT; ++t) {
        const int b  = t % 3;
        const int pb = (t + 2) % 3;
        const int8_t* bA = lds + (b * 2 + 0) * BUF_SZ;
        const int8_t* bB = lds + (b * 2 + 1) * BUF_SZ;

        // issue next-next tile staging first (earliest in flight)
        if (t + 2 < NT) {
            STAGE(pb, 0, 0, t + 2); STAGE(pb, 0, 1, t + 2);
            STAGE(pb, 1, 0, t + 2); STAGE(pb, 1, 1, t + 2);
        }

        // read all fragments; compiler interleaves with MFMA via lgkmcnt
        v4i bF[4], aF[8];
#pragma unroll
        for (int ni = 0; ni < 4; ++ni) bF[ni] = *(const v4i*)(bB + offB[ni]);
#pragma unroll
        for (int mi = 0; mi < 8; ++mi) aF[mi] = *(const v4i*)(bA + offA[mi]);

        __builtin_amdgcn_s_setprio(1);
#pragma unroll
        for (int mi = 0; mi < 8; ++mi)
#pragma unroll
            for (int ni = 0; ni < 4; ++ni)
                acc[mi][ni] = __builtin_amdgcn_mfma_i32_16x16x64_i8(
                    aF[mi], bF[ni], acc[mi][ni], 0, 0, 0);
        __builtin_amdgcn_s_setprio(0);

        if (t < NT - 2) asm volatile("s_waitcnt vmcnt(4)" ::: "memory");
        else            asm volatile("s_waitcnt vmcnt(0)" ::: "memory");
        __builtin_amdgcn_s_barrier();
        asm volatile("" ::: "memory");
    }

    // epilogue (r17/r18-verified mapping; bf16-exact values in f32 slots)
    const int row0 = bm * BM + wm * 128 + (lane >> 4) * 4;
    const int col0 = bn * BN + wn * 64 + (lane & 15);
#pragma unroll
    for (int mi = 0; mi < 8; ++mi) {
#pragma unroll
        for (int j = 0; j < 4; ++j) {
            const int row = row0 + mi * 16 + j;
            const float xscale = xs[row];
#pragma unroll
            for (int ni = 0; ni < 4; ++ni) {
                const int col = col0 + ni * 16;
                float p_  = (float)acc[mi][ni][j] * xscale * wsc[col];
                float pb_ = __bfloat162float(__float2bfloat16(p_));
                float vb  = __bfloat162float(__float2bfloat16(
                                pb_ + __bfloat162float(bias[col])));
                out[(size_t)row * N_DIM + col] = vb;
            }
        }
    }
#undef STAGE
}

// ---------------------------------------------------------------------------
extern "C" void kernel_launch(void* const* d_in, const int* in_sizes, int n_in,
                              void* d_out, int out_size, void* d_ws, size_t ws_size,
                              hipStream_t stream)
{
    const float*          x    = (const float*)d_in[0];
    const int*            w32  = (const int*)d_in[1];
    const float*          wsc  = (const float*)d_in[2];
    const __hip_bfloat16* bias = (const __hip_bfloat16*)d_in[3];
    float*                out  = (float*)d_out;

    int8_t* xq = (int8_t*)d_ws + XQ_OFF;
    float*  xs = (float*)((char*)d_ws + XS_OFF);
    int8_t* w8 = (int8_t*)d_ws + W8_OFF;

    prep_kernel<<<T_DIM / 4 + (N_DIM * (K_DIM / 16)) / 256, 256, 0, stream>>>(
        x, xq, xs, w32, w8);
    gemm_i8_kernel<<<(T_DIM / BM) * (N_DIM / BN), 512, 0, stream>>>(
        xq, w8, xs, wsc, bias, out);
}